// Round 1
// baseline (695.926 us; speedup 1.0000x reference)
//
#include <hip/hip_runtime.h>

#define TP 32   // positions per workgroup

// Dims (fixed by the problem)
//   B=8, IN=256, HEADS=8, KEY=64, MEM=64, HEAD_DIM=64, OUT=256, HW=4096
// Channel split for in-proj: 512 channels -> (KEY k outer, HEADS n inner): row = k*8 + n
// Channel merge for out-proj: hidden channel c' = n*64 + d

__global__ __launch_bounds__(256) void fused_kcmm(
    const float* __restrict__ x, const float* __restrict__ key_p,
    const float* __restrict__ memory, const float* __restrict__ w_in,
    const float* __restrict__ b_in, const float* __restrict__ w_out,
    const float* __restrict__ b_out, float* __restrict__ out)
{
    __shared__ float Xs[256 * TP];   // [c][p]  32 KB
    __shared__ float Ws[64 * 64];    // phase A: [cc][o] w_in slice; phase C: [dd][o] w_out slice (16 KB)
    __shared__ float Ybuf[64 * 33];  // aliased y1 -> probs -> hidden, padded stride 33 (8.25 KB)
    __shared__ float red[8 * 32];    // softmax partial reduce
    __shared__ float gred[32];       // softmax global max / inv-sum

    const int t  = threadIdx.x;
    const int wg = blockIdx.x;
    const int b   = wg >> 7;          // wg*32/4096
    const int hw0 = (wg & 127) * TP;
    const float* xb = x + (size_t)b * 256 * 4096 + hw0;

    // ---- stage x tile: Xs[c][p] ----
    for (int i = 0; i < 8; ++i) {
        int c  = i * 32 + (t >> 3);
        int p4 = (t & 7) * 4;
        float4 v = *(const float4*)(xb + (size_t)c * 4096 + p4);
        *(float4*)(&Xs[c * TP + p4]) = v;
    }

    // ---- phase C accumulators: thread (oL = t&31, pgC = t>>5): o = oL+32*i, p = pgC*4+j ----
    const int oL  = t & 31;
    const int pgC = t >> 5;
    float Cacc[8][4];
    #pragma unroll
    for (int i = 0; i < 8; ++i)
        #pragma unroll
        for (int j = 0; j < 4; ++j) Cacc[i][j] = 0.f;

    const int oA  = t & 63;   // phase A: k index
    const int pgA = t >> 6;   // 0..3 -> p = pgA*8+j
    const int pB  = t & 31;   // phase B: position
    const int mg  = t >> 5;   // 0..7  -> m/d = mg*8+j

    for (int n = 0; n < 8; ++n) {
        // ================= phase A: y1[k][p] = sum_c w_in[k*8+n][c] * x[c][p] =================
        float acc[8];
        #pragma unroll
        for (int j = 0; j < 8; ++j) acc[j] = 0.f;

        for (int s = 0; s < 4; ++s) {
            __syncthreads();  // Ws free (prev use done)
            {   // stage Ws[cc][o] = w_in[(o*8+n)*256 + s*64 + cc]
                int o   = t >> 2;
                int cc0 = (t & 3) * 16;
                const float* src = w_in + (size_t)(o * 8 + n) * 256 + s * 64 + cc0;
                #pragma unroll
                for (int q = 0; q < 4; ++q) {
                    float4 v = *(const float4*)(src + q * 4);
                    Ws[(cc0 + q * 4 + 0) * 64 + o] = v.x;
                    Ws[(cc0 + q * 4 + 1) * 64 + o] = v.y;
                    Ws[(cc0 + q * 4 + 2) * 64 + o] = v.z;
                    Ws[(cc0 + q * 4 + 3) * 64 + o] = v.w;
                }
            }
            __syncthreads();
            #pragma unroll 8
            for (int cc = 0; cc < 64; ++cc) {
                float w = Ws[cc * 64 + oA];
                const float* xr = &Xs[(s * 64 + cc) * TP + pgA * 8];
                #pragma unroll
                for (int j = 0; j < 8; ++j) acc[j] += w * xr[j];
            }
        }

        __syncthreads();  // Ybuf free (prev head's phase C reads done)
        {
            float bi = b_in[oA * 8 + n];
            #pragma unroll
            for (int j = 0; j < 8; ++j) Ybuf[oA * 33 + pgA * 8 + j] = acc[j] + bi;
        }
        __syncthreads();

        // ================= logits[m][p] = sum_k key_p[n][k][m] * y1[k][p] =================
        float lg[8];
        #pragma unroll
        for (int j = 0; j < 8; ++j) lg[j] = 0.f;
        const float* kp = key_p + (size_t)n * 4096 + mg * 8;
        for (int k = 0; k < 64; ++k) {
            float y  = Ybuf[k * 33 + pB];
            float4 a = *(const float4*)(kp + k * 64);
            float4 c4 = *(const float4*)(kp + k * 64 + 4);
            lg[0] += a.x * y;  lg[1] += a.y * y;  lg[2] += a.z * y;  lg[3] += a.w * y;
            lg[4] += c4.x * y; lg[5] += c4.y * y; lg[6] += c4.z * y; lg[7] += c4.w * y;
        }

        // ---- softmax over m per position ----
        float lmax = lg[0];
        #pragma unroll
        for (int j = 1; j < 8; ++j) lmax = fmaxf(lmax, lg[j]);
        red[mg * 32 + pB] = lmax;
        __syncthreads();
        if (t < 32) {
            float m0 = red[t];
            #pragma unroll
            for (int g = 1; g < 8; ++g) m0 = fmaxf(m0, red[g * 32 + t]);
            gred[t] = m0;
        }
        __syncthreads();
        float gm = gred[pB];
        float e[8]; float lsum = 0.f;
        #pragma unroll
        for (int j = 0; j < 8; ++j) { e[j] = __expf(lg[j] - gm); lsum += e[j]; }
        red[mg * 32 + pB] = lsum;
        __syncthreads();
        if (t < 32) {
            float s0 = 0.f;
            #pragma unroll
            for (int g = 0; g < 8; ++g) s0 += red[g * 32 + t];
            gred[t] = 1.0f / s0;
        }
        __syncthreads();
        float inv = gred[pB];
        #pragma unroll
        for (int j = 0; j < 8; ++j) Ybuf[(mg * 8 + j) * 33 + pB] = e[j] * inv;  // probs over Ybuf
        __syncthreads();

        // ================= hidden[d][p] = sum_m memory[n][m][d] * probs[m][p] =================
        float h[8];
        #pragma unroll
        for (int j = 0; j < 8; ++j) h[j] = 0.f;
        const float* mem = memory + (size_t)n * 4096 + mg * 8;
        for (int m = 0; m < 64; ++m) {
            float pr = Ybuf[m * 33 + pB];
            float4 a = *(const float4*)(mem + m * 64);
            float4 c4 = *(const float4*)(mem + m * 64 + 4);
            h[0] += a.x * pr;  h[1] += a.y * pr;  h[2] += a.z * pr;  h[3] += a.w * pr;
            h[4] += c4.x * pr; h[5] += c4.y * pr; h[6] += c4.z * pr; h[7] += c4.w * pr;
        }
        __syncthreads();
        #pragma unroll
        for (int j = 0; j < 8; ++j) Ybuf[(mg * 8 + j) * 33 + pB] = h[j];  // hidden over Ybuf
        __syncthreads();

        // ================= phase C: Cacc[o][p] += sum_d w_out[o][n*64+d] * hidden[d][p] =================
        for (int s = 0; s < 4; ++s) {
            {   // stage Ws[dd][o] = w_out[o*512 + n*64 + s*16 + dd], thread owns row o = t
                const float* src = w_out + (size_t)t * 512 + n * 64 + s * 16;
                float4 v0 = *(const float4*)(src);
                float4 v1 = *(const float4*)(src + 4);
                float4 v2 = *(const float4*)(src + 8);
                float4 v3 = *(const float4*)(src + 12);
                float tmp[16] = {v0.x, v0.y, v0.z, v0.w, v1.x, v1.y, v1.z, v1.w,
                                 v2.x, v2.y, v2.z, v2.w, v3.x, v3.y, v3.z, v3.w};
                #pragma unroll
                for (int q = 0; q < 16; ++q) Ws[q * 256 + t] = tmp[q];
            }
            __syncthreads();
            #pragma unroll
            for (int dd = 0; dd < 16; ++dd) {
                int d = s * 16 + dd;
                float hv[4];
                #pragma unroll
                for (int j = 0; j < 4; ++j) hv[j] = Ybuf[d * 33 + pgC * 4 + j];
                #pragma unroll
                for (int i = 0; i < 8; ++i) {
                    float wv = Ws[dd * 256 + oL + 32 * i];
                    #pragma unroll
                    for (int j = 0; j < 4; ++j) Cacc[i][j] += wv * hv[j];
                }
            }
            __syncthreads();  // Ws free before restage / next head
        }
    }

    // ---- epilogue: out[b][o][hw0+p] = Cacc + b_out[o] ----
    #pragma unroll
    for (int i = 0; i < 8; ++i) {
        int o = oL + 32 * i;
        float bo = b_out[o];
        float4 v = {Cacc[i][0] + bo, Cacc[i][1] + bo, Cacc[i][2] + bo, Cacc[i][3] + bo};
        *(float4*)(out + ((size_t)b * 256 + o) * 4096 + hw0 + pgC * 4) = v;
    }
}

extern "C" void kernel_launch(void* const* d_in, const int* in_sizes, int n_in,
                              void* d_out, int out_size, void* d_ws, size_t ws_size,
                              hipStream_t stream) {
    (void)in_sizes; (void)n_in; (void)d_ws; (void)ws_size; (void)out_size;
    const float* x      = (const float*)d_in[0];
    const float* key_p  = (const float*)d_in[1];
    const float* memory = (const float*)d_in[2];
    const float* w_in   = (const float*)d_in[3];
    const float* b_in   = (const float*)d_in[4];
    const float* w_out  = (const float*)d_in[5];
    const float* b_out  = (const float*)d_in[6];
    float* out = (float*)d_out;

    // 32768 positions / TP=32 -> 1024 workgroups
    fused_kcmm<<<1024, 256, 0, stream>>>(x, key_p, memory, w_in, b_in, w_out, b_out, out);
}

// Round 2
// 131.743 us; speedup vs baseline: 5.2825x; 5.2825x over previous
//
#include <hip/hip_runtime.h>

// B=8, IN=256, HEADS=8, KEY=64, MEM=64, HEAD_DIM=64, OUT=256, HW=4096
// Folded form:
//   logits[(n,m)][pos] = A[(n,m)][c] @ x[c][pos] + bb[(n,m)]   (512x256 GEMM)
//   probs = softmax over m (64-row groups)
//   out[o][pos] = M[o][(n,m)] @ probs + b_out[o]               (256x512 GEMM)

typedef _Float16 half8 __attribute__((ext_vector_type(8)));
typedef _Float16 half4 __attribute__((ext_vector_type(4)));
typedef _Float16 half2v __attribute__((ext_vector_type(2)));
typedef float float4v __attribute__((ext_vector_type(4)));

// ---------------- fold kernels (tiny) ----------------
// Aswz layout: element (row, k): R=row/16, s=k/32, l=(row%16)+16*((k%32)/8), i=k%8
//   index = ((R*8+s)*64 + l)*8 + i   (A-fragment layout for mfma_f32_16x16x32_f16)
__global__ void fold_a(const float* __restrict__ key_p, const float* __restrict__ w_in,
                       const float* __restrict__ b_in, _Float16* __restrict__ Aswz,
                       float* __restrict__ bb) {
    int row = blockIdx.x;      // 0..511 = n*64+m
    int c   = threadIdx.x;     // 0..255
    int n = row >> 6, m = row & 63;
    float v = 0.f;
    for (int k = 0; k < 64; ++k)
        v += key_p[n * 4096 + k * 64 + m] * w_in[(k * 8 + n) * 256 + c];
    int R = row >> 4, s = c >> 5, i = c & 7, lsub = (c >> 3) & 3;
    int l = (row & 15) + 16 * lsub;
    Aswz[(((R * 8 + s) * 64 + l) << 3) + i] = (_Float16)v;
    if (c == 0) {
        float s2 = 0.f;
        for (int k = 0; k < 64; ++k)
            s2 += key_p[n * 4096 + k * 64 + m] * b_in[k * 8 + n];
        bb[row] = s2;
    }
}

// Mswz layout: element (o, col): R2=o/16, s=col/32, l=(o%16)+16*((col%32)/8), i=col%8
//   index = ((R2*16+s)*64 + l)*8 + i
__global__ void fold_m(const float* __restrict__ w_out, const float* __restrict__ memory,
                       _Float16* __restrict__ Mswz) {
    int o = blockIdx.x;        // 0..255
    int t = threadIdx.x;       // 0..255
    for (int hh = 0; hh < 2; ++hh) {
        int col = t + hh * 256;   // 0..511 = n*64+m
        int n = col >> 6, m = col & 63;
        float v = 0.f;
        for (int d = 0; d < 64; ++d)
            v += w_out[o * 512 + n * 64 + d] * memory[n * 4096 + m * 64 + d];
        int R2 = o >> 4, s = col >> 5, i = col & 7;
        int l = (o & 15) + 16 * ((col >> 3) & 3);
        Mswz[(((R2 * 16 + s) * 64 + l) << 3) + i] = (_Float16)v;
    }
}

// ---------------- main fused kernel ----------------
// 512 WGs x 256 threads; each WG: 64 positions, full 512-row logits via MFMA.
// Wave w owns logit rows w*128..w*128+127 (heads n=2w,2w+1) over all 64 positions.
#define XS_STRIDE 264   // halves per p-row for Xs  [64][256]+pad
#define PR_STRIDE 520   // halves per p-row for Prs [64][512]+pad

__global__ __launch_bounds__(256, 2) void fused_main(
    const float* __restrict__ x, const _Float16* __restrict__ Aswz,
    const float* __restrict__ bb, const _Float16* __restrict__ Mswz,
    const float* __restrict__ b_out, float* __restrict__ out)
{
    __shared__ _Float16 S[64 * PR_STRIDE];   // 66560 B; Xs (stride 264) aliased with Prs (stride 520)

    const int t  = threadIdx.x;
    const int w  = t >> 6;          // wave 0..3
    const int l  = t & 63;          // lane
    const int q  = l >> 4;          // quadrant 0..3
    const int lp = l & 15;
    const int wg  = blockIdx.x;
    const int b   = wg >> 6;
    const int hw0 = (wg & 63) * 64;
    const float* xb = x + (size_t)b * 256 * 4096 + hw0;

    // ---- stage Xs[p][c] fp16 (transposed), 2-way max bank aliasing ----
    #pragma unroll
    for (int i = 0; i < 8; ++i) {
        int u  = i * 256 + t;
        int cp = u & 127;           // c-pair
        int qq = u >> 7;            // p-quad 0..15
        int c0 = cp * 2, p4 = qq * 4;
        const float* px = xb + (size_t)c0 * 4096 + p4;
        float4 v0 = *(const float4*)(px);
        float4 v1 = *(const float4*)(px + 4096);
        *(half2v*)(&S[(p4 + 0) * XS_STRIDE + c0]) = half2v{(_Float16)v0.x, (_Float16)v1.x};
        *(half2v*)(&S[(p4 + 1) * XS_STRIDE + c0]) = half2v{(_Float16)v0.y, (_Float16)v1.y};
        *(half2v*)(&S[(p4 + 2) * XS_STRIDE + c0]) = half2v{(_Float16)v0.z, (_Float16)v1.z};
        *(half2v*)(&S[(p4 + 3) * XS_STRIDE + c0]) = half2v{(_Float16)v0.w, (_Float16)v1.w};
    }
    __syncthreads();

    // ---- GEMM1: logits[512 x 64], wave w -> row-tiles R = w*8 + r ----
    float4v acc[8][4];
    #pragma unroll
    for (int r = 0; r < 8; ++r)
        #pragma unroll
        for (int c = 0; c < 4; ++c) acc[r][c] = float4v{0.f, 0.f, 0.f, 0.f};

    const half8* Ag = (const half8*)Aswz;
    for (int s = 0; s < 8; ++s) {
        half8 bf[4];
        #pragma unroll
        for (int c = 0; c < 4; ++c)
            bf[c] = *(const half8*)(&S[(c * 16 + lp) * XS_STRIDE + s * 32 + q * 8]);
        half8 af[8];
        #pragma unroll
        for (int r = 0; r < 8; ++r)
            af[r] = Ag[((w * 8 + r) * 8 + s) * 64 + l];
        #pragma unroll
        for (int r = 0; r < 8; ++r)
            #pragma unroll
            for (int c = 0; c < 4; ++c)
                acc[r][c] = __builtin_amdgcn_mfma_f32_16x16x32_f16(af[r], bf[c], acc[r][c], 0, 0, 0);
    }

    // ---- bias ----
    #pragma unroll
    for (int r = 0; r < 8; ++r) {
        float4v bbv = *(const float4v*)(bb + w * 128 + r * 16 + q * 4);
        #pragma unroll
        for (int c = 0; c < 4; ++c)
            #pragma unroll
            for (int j = 0; j < 4; ++j) acc[r][c][j] += bbv[j];
    }

    __syncthreads();   // all waves done reading Xs (Prs aliases it)

    // ---- softmax over each head's 64 rows (within-wave; lanes l, l^16, l^32, l^48 share a column) ----
    #pragma unroll
    for (int h = 0; h < 2; ++h) {
        #pragma unroll
        for (int c = 0; c < 4; ++c) {
            float mx = -1e30f;
            #pragma unroll
            for (int rr = 0; rr < 4; ++rr) {
                int r = h * 4 + rr;
                #pragma unroll
                for (int j = 0; j < 4; ++j) mx = fmaxf(mx, acc[r][c][j]);
            }
            mx = fmaxf(mx, __shfl_xor(mx, 16, 64));
            mx = fmaxf(mx, __shfl_xor(mx, 32, 64));
            float sum = 0.f;
            #pragma unroll
            for (int rr = 0; rr < 4; ++rr) {
                int r = h * 4 + rr;
                #pragma unroll
                for (int j = 0; j < 4; ++j) {
                    float e = __expf(acc[r][c][j] - mx);
                    acc[r][c][j] = e;
                    sum += e;
                }
            }
            sum += __shfl_xor(sum, 16, 64);
            sum += __shfl_xor(sum, 32, 64);
            float inv = 1.f / sum;
            #pragma unroll
            for (int rr = 0; rr < 4; ++rr) {
                int r = h * 4 + rr;
                half4 pv = {(_Float16)(acc[r][c][0] * inv), (_Float16)(acc[r][c][1] * inv),
                            (_Float16)(acc[r][c][2] * inv), (_Float16)(acc[r][c][3] * inv)};
                *(half4*)(&S[(c * 16 + lp) * PR_STRIDE + w * 128 + r * 16 + q * 4]) = pv;
            }
        }
    }
    __syncthreads();

    // ---- GEMM2: out[256 x 64] = M[256x512] @ probs, wave w -> out rows w*64..w*64+63 ----
    float4v acc2[4][4];
    #pragma unroll
    for (int r = 0; r < 4; ++r)
        #pragma unroll
        for (int c = 0; c < 4; ++c) acc2[r][c] = float4v{0.f, 0.f, 0.f, 0.f};

    const half8* Mg = (const half8*)Mswz;
    for (int s2 = 0; s2 < 16; ++s2) {
        half8 bf2[4];
        #pragma unroll
        for (int c = 0; c < 4; ++c)
            bf2[c] = *(const half8*)(&S[(c * 16 + lp) * PR_STRIDE + s2 * 32 + q * 8]);
        half8 af2[4];
        #pragma unroll
        for (int r = 0; r < 4; ++r)
            af2[r] = Mg[((w * 4 + r) * 16 + s2) * 64 + l];
        #pragma unroll
        for (int r = 0; r < 4; ++r)
            #pragma unroll
            for (int c = 0; c < 4; ++c)
                acc2[r][c] = __builtin_amdgcn_mfma_f32_16x16x32_f16(af2[r], bf2[c], acc2[r][c], 0, 0, 0);
    }

    // ---- epilogue ----
    #pragma unroll
    for (int r = 0; r < 4; ++r) {
        int ob = w * 64 + r * 16 + q * 4;
        float4v bo = *(const float4v*)(b_out + ob);
        #pragma unroll
        for (int j = 0; j < 4; ++j) {
            float* orow = out + ((size_t)b * 256 + ob + j) * 4096 + hw0;
            #pragma unroll
            for (int c = 0; c < 4; ++c)
                orow[c * 16 + lp] = acc2[r][c][j] + bo[j];
        }
    }
}

extern "C" void kernel_launch(void* const* d_in, const int* in_sizes, int n_in,
                              void* d_out, int out_size, void* d_ws, size_t ws_size,
                              hipStream_t stream) {
    (void)in_sizes; (void)n_in; (void)ws_size; (void)out_size;
    const float* x      = (const float*)d_in[0];
    const float* key_p  = (const float*)d_in[1];
    const float* memory = (const float*)d_in[2];
    const float* w_in   = (const float*)d_in[3];
    const float* b_in   = (const float*)d_in[4];
    const float* w_out  = (const float*)d_in[5];
    const float* b_out  = (const float*)d_in[6];
    float* out = (float*)d_out;

    _Float16* Aswz = (_Float16*)d_ws;                       // 512*256 fp16 = 256 KB
    _Float16* Mswz = Aswz + 512 * 256;                      // 256*512 fp16 = 256 KB
    float*    bb   = (float*)(Mswz + 256 * 512);            // 512 fp32

    fold_a<<<512, 256, 0, stream>>>(key_p, w_in, b_in, Aswz, bb);
    fold_m<<<256, 256, 0, stream>>>(w_out, memory, Mswz);
    fused_main<<<512, 256, 0, stream>>>(x, Aswz, bb, Mswz, b_out, out);
}

// Round 3
// 120.192 us; speedup vs baseline: 5.7901x; 1.0961x over previous
//
#include <hip/hip_runtime.h>

// B=8, IN=256, HEADS=8, KEY=64, MEM=64, HEAD_DIM=64, OUT=256, HW=4096
// Folded form:
//   logits[(n,m)][pos] = A[(n,m)][c] @ x[c][pos] + bb[(n,m)]   (512x256 GEMM)
//   probs = softmax over m (64-row groups)
//   out[o][pos] = M[o][(n,m)] @ probs + b_out[o]               (256x512 GEMM)

typedef _Float16 half8 __attribute__((ext_vector_type(8)));
typedef _Float16 half4 __attribute__((ext_vector_type(4)));
typedef _Float16 half2v __attribute__((ext_vector_type(2)));
typedef float float4v __attribute__((ext_vector_type(4)));

// ---------------- merged fold kernel ----------------
// blocks 0..511: A row (n*64+m); blocks 512..767: M row (o)
// Aswz fragment layout (A-operand of mfma_f32_16x16x32_f16):
//   (row,k): idx = (((row/16)*8 + k/32)*64 + (row%16) + 16*((k%32)/8))*8 + k%8
// Mswz: (o,col): idx = (((o/16)*16 + col/32)*64 + (o%16) + 16*((col%32)/8))*8 + col%8
__global__ __launch_bounds__(256) void fold_all(
    const float* __restrict__ key_p, const float* __restrict__ w_in,
    const float* __restrict__ b_in, const float* __restrict__ w_out,
    const float* __restrict__ memory,
    _Float16* __restrict__ Aswz, _Float16* __restrict__ Mswz, float* __restrict__ bb)
{
    __shared__ float sv[512];
    __shared__ float red[64];
    const int blk = blockIdx.x;
    const int t = threadIdx.x;

    if (blk < 512) {
        const int row = blk, n = row >> 6, m = row & 63;
        if (t < 64) sv[t] = key_p[n * 4096 + t * 64 + m];   // key column
        __syncthreads();
        const int c = t;
        float v = 0.f;
        #pragma unroll 8
        for (int k = 0; k < 64; ++k)
            v = fmaf(sv[k], w_in[(k * 8 + n) * 256 + c], v);
        int R = row >> 4, s = c >> 5, i = c & 7;
        int l = (row & 15) + 16 * ((c >> 3) & 3);
        Aswz[(((R * 8 + s) * 64 + l) << 3) + i] = (_Float16)v;
        if (t < 64) red[t] = sv[t] * b_in[t * 8 + n];
        __syncthreads();
        if (t == 0) {
            float s2 = 0.f;
            for (int k = 0; k < 64; ++k) s2 += red[k];
            bb[row] = s2;
        }
    } else {
        const int o = blk - 512;
        sv[t]       = w_out[o * 512 + t];
        sv[256 + t] = w_out[o * 512 + 256 + t];
        __syncthreads();
        #pragma unroll
        for (int hh = 0; hh < 2; ++hh) {
            int col = t + hh * 256, n = col >> 6, m = col & 63;
            const float4* mrow = (const float4*)(memory + n * 4096 + m * 64);
            const float4* wrow = (const float4*)(sv + n * 64);
            float v = 0.f;
            #pragma unroll
            for (int qd = 0; qd < 16; ++qd) {
                float4 a = mrow[qd], w = wrow[qd];
                v += a.x * w.x + a.y * w.y + a.z * w.z + a.w * w.w;
            }
            int R2 = o >> 4, s = col >> 5, i = col & 7;
            int l = (o & 15) + 16 * ((col >> 3) & 3);
            Mswz[(((R2 * 16 + s) * 64 + l) << 3) + i] = (_Float16)v;
        }
    }
}

// ---------------- main fused kernel ----------------
// 512 WGs x 256 threads; each WG: 64 positions, full 512-row logits via MFMA.
// Wave w owns logit rows w*128..w*128+127 (heads 2w, 2w+1).
// LDS: one 64 KB buffer. Phase 1: Xs[p][c] fp16, stride 264 (33.8 KB, aliased).
// Phase 2: P in B-fragment layout, 64 chunks (s2,ct) x 64 lanes x 8 halves = 64 KB exact.
#define XS_STRIDE 264

__global__ __launch_bounds__(256, 2) void fused_main(
    const float* __restrict__ x, const _Float16* __restrict__ Aswz,
    const float* __restrict__ bb, const _Float16* __restrict__ Mswz,
    const float* __restrict__ b_out, float* __restrict__ out)
{
    __shared__ _Float16 S[32768];   // 64 KB

    const int t  = threadIdx.x;
    const int w  = t >> 6;          // wave 0..3
    const int l  = t & 63;          // lane
    const int q  = l >> 4;          // quadrant 0..3
    const int lp = l & 15;
    const int wg  = blockIdx.x;
    const int b   = wg >> 6;
    const int hw0 = (wg & 63) * 64;
    const float* xb = x + (size_t)b * 256 * 4096 + hw0;

    // ---- stage Xs[p][c] fp16 (transposed) ----
    #pragma unroll
    for (int i = 0; i < 8; ++i) {
        int u  = i * 256 + t;
        int cp = u & 127;           // channel pair
        int qq = u >> 7;            // position quad 0..15
        int c0 = cp * 2, p4 = qq * 4;
        const float* px = xb + (size_t)c0 * 4096 + p4;
        float4 v0 = *(const float4*)(px);
        float4 v1 = *(const float4*)(px + 4096);
        *(half2v*)(&S[(p4 + 0) * XS_STRIDE + c0]) = half2v{(_Float16)v0.x, (_Float16)v1.x};
        *(half2v*)(&S[(p4 + 1) * XS_STRIDE + c0]) = half2v{(_Float16)v0.y, (_Float16)v1.y};
        *(half2v*)(&S[(p4 + 2) * XS_STRIDE + c0]) = half2v{(_Float16)v0.z, (_Float16)v1.z};
        *(half2v*)(&S[(p4 + 3) * XS_STRIDE + c0]) = half2v{(_Float16)v0.w, (_Float16)v1.w};
    }
    __syncthreads();

    // ---- GEMM1: logits[512 x 64] ----
    float4v acc[8][4];
    #pragma unroll
    for (int r = 0; r < 8; ++r)
        #pragma unroll
        for (int c = 0; c < 4; ++c) acc[r][c] = float4v{0.f, 0.f, 0.f, 0.f};

    const half8* Ag = (const half8*)Aswz;
    for (int s = 0; s < 8; ++s) {
        half8 bf[4];
        #pragma unroll
        for (int c = 0; c < 4; ++c)
            bf[c] = *(const half8*)(&S[(c * 16 + lp) * XS_STRIDE + s * 32 + q * 8]);
        half8 af[8];
        #pragma unroll
        for (int r = 0; r < 8; ++r)
            af[r] = Ag[((w * 8 + r) * 8 + s) * 64 + l];
        #pragma unroll
        for (int r = 0; r < 8; ++r)
            #pragma unroll
            for (int c = 0; c < 4; ++c)
                acc[r][c] = __builtin_amdgcn_mfma_f32_16x16x32_f16(af[r], bf[c], acc[r][c], 0, 0, 0);
    }

    // ---- bias ----
    #pragma unroll
    for (int r = 0; r < 8; ++r) {
        float4v bbv = *(const float4v*)(bb + w * 128 + r * 16 + q * 4);
        #pragma unroll
        for (int c = 0; c < 4; ++c)
            #pragma unroll
            for (int j = 0; j < 4; ++j) acc[r][c][j] += bbv[j];
    }

    __syncthreads();   // all waves done reading Xs (P region aliases it)

    // ---- softmax + store P in B-fragment layout ----
    // row = w*128 + r*16 + q*4 + j, col = c*16+lp
    // s2 = w*4 + (r>>1); lane' = ((r&1)*2 + (q>>1))*16 + lp; i0 = (q&1)*4
    #pragma unroll
    for (int h = 0; h < 2; ++h) {
        #pragma unroll
        for (int c = 0; c < 4; ++c) {
            float mx = -1e30f;
            #pragma unroll
            for (int rr = 0; rr < 4; ++rr) {
                int r = h * 4 + rr;
                #pragma unroll
                for (int j = 0; j < 4; ++j) mx = fmaxf(mx, acc[r][c][j]);
            }
            mx = fmaxf(mx, __shfl_xor(mx, 16, 64));
            mx = fmaxf(mx, __shfl_xor(mx, 32, 64));
            float sum = 0.f;
            #pragma unroll
            for (int rr = 0; rr < 4; ++rr) {
                int r = h * 4 + rr;
                #pragma unroll
                for (int j = 0; j < 4; ++j) {
                    float e = __expf(acc[r][c][j] - mx);
                    acc[r][c][j] = e;
                    sum += e;
                }
            }
            sum += __shfl_xor(sum, 16, 64);
            sum += __shfl_xor(sum, 32, 64);
            float inv = 1.f / sum;
            #pragma unroll
            for (int rr = 0; rr < 4; ++rr) {
                int r = h * 4 + rr;
                int s2 = w * 4 + (r >> 1);
                int lq = ((r & 1) * 2 + (q >> 1)) * 16 + lp;
                int i0 = (q & 1) * 4;
                half4 pv = {(_Float16)(acc[r][c][0] * inv), (_Float16)(acc[r][c][1] * inv),
                            (_Float16)(acc[r][c][2] * inv), (_Float16)(acc[r][c][3] * inv)};
                *(half4*)(&S[(((s2 * 4 + c) * 64) + lq) * 8 + i0]) = pv;
            }
        }
    }
    __syncthreads();

    // ---- GEMM2: out[256 x 64] = M[256x512] @ P ----
    float4v acc2[4][4];
    #pragma unroll
    for (int r = 0; r < 4; ++r)
        #pragma unroll
        for (int c = 0; c < 4; ++c) acc2[r][c] = float4v{0.f, 0.f, 0.f, 0.f};

    const half8* Mg = (const half8*)Mswz;
    for (int s2 = 0; s2 < 16; ++s2) {
        half8 bf2[4];
        #pragma unroll
        for (int c = 0; c < 4; ++c)
            bf2[c] = *(const half8*)(&S[(((s2 * 4 + c) * 64) + l) * 8]);   // conflict-free b128
        half8 af2[4];
        #pragma unroll
        for (int r = 0; r < 4; ++r)
            af2[r] = Mg[((w * 4 + r) * 16 + s2) * 64 + l];
        #pragma unroll
        for (int r = 0; r < 4; ++r)
            #pragma unroll
            for (int c = 0; c < 4; ++c)
                acc2[r][c] = __builtin_amdgcn_mfma_f32_16x16x32_f16(af2[r], bf2[c], acc2[r][c], 0, 0, 0);
    }

    // ---- epilogue ----
    #pragma unroll
    for (int r = 0; r < 4; ++r) {
        int ob = w * 64 + r * 16 + q * 4;
        float4v bo = *(const float4v*)(b_out + ob);
        #pragma unroll
        for (int j = 0; j < 4; ++j) {
            float* orow = out + ((size_t)b * 256 + ob + j) * 4096 + hw0;
            #pragma unroll
            for (int c = 0; c < 4; ++c)
                orow[c * 16 + lp] = acc2[r][c][j] + bo[j];
        }
    }
}

extern "C" void kernel_launch(void* const* d_in, const int* in_sizes, int n_in,
                              void* d_out, int out_size, void* d_ws, size_t ws_size,
                              hipStream_t stream) {
    (void)in_sizes; (void)n_in; (void)ws_size; (void)out_size;
    const float* x      = (const float*)d_in[0];
    const float* key_p  = (const float*)d_in[1];
    const float* memory = (const float*)d_in[2];
    const float* w_in   = (const float*)d_in[3];
    const float* b_in   = (const float*)d_in[4];
    const float* w_out  = (const float*)d_in[5];
    const float* b_out  = (const float*)d_in[6];
    float* out = (float*)d_out;

    _Float16* Aswz = (_Float16*)d_ws;                       // 512*256 fp16 = 256 KB
    _Float16* Mswz = Aswz + 512 * 256;                      // 256*512 fp16 = 256 KB
    float*    bb   = (float*)(Mswz + 256 * 512);            // 512 fp32

    fold_all<<<768, 256, 0, stream>>>(key_p, w_in, b_in, w_out, memory, Aswz, Mswz, bb);
    fused_main<<<512, 256, 0, stream>>>(x, Aswz, bb, Mswz, b_out, out);
}